// Round 1
// 381.174 us; speedup vs baseline: 1.0907x; 1.0907x over previous
//
#include <hip/hip_runtime.h>
#include <math.h>

#define N 8192
typedef unsigned long long u64;

// ---------------------------------------------------------------------------
// Kernel A: h = W @ x + b (+ emit stable-sort key record).
// R4 change: 512-thread blocks (8 waves = 8 rows), __launch_bounds__(512, 8)
// to force VGPR<=64 so 4 blocks/CU co-reside (32 waves/CU, LDS 4x32KB=128KB)
// -- the occupancy regime where float4 streams hit ~6.3 TB/s. Unroll dropped
// 16->8 to fit the VGPR budget without spills. Per-lane fma chain and the
// shuffle tree are BIT-IDENTICAL to the verified R3 version (only the
// row->block mapping changed, which no lane's arithmetic depends on).
// ---------------------------------------------------------------------------
__global__ __launch_bounds__(512, 8) void matvec_k(const float* __restrict__ W,
                                                   const float* __restrict__ x,
                                                   const float* __restrict__ b,
                                                   const float* __restrict__ c,
                                                   float* __restrict__ h,
                                                   u64* __restrict__ Kkey) {
  __shared__ float xs[N];  // 32 KiB
  const int tid = threadIdx.x;
  {
    const float4* x4 = reinterpret_cast<const float4*>(x);
    float4* xs4 = reinterpret_cast<float4*>(xs);
#pragma unroll
    for (int j = 0; j < 4; ++j) xs4[j * 512 + tid] = x4[j * 512 + tid];
  }
  __syncthreads();

  const int lane = tid & 63;
  const int wid = tid >> 6;                 // 0..7
  const int row = blockIdx.x * 8 + wid;
  const float4* Wr = reinterpret_cast<const float4*>(W + (size_t)row * N);
  const float4* xs4 = reinterpret_cast<const float4*>(xs);
  float acc = 0.f;
#pragma unroll 8
  for (int k = 0; k < 32; ++k) {
    const int i = k * 64 + lane;
    const float4 w = Wr[i];
    const float4 xv = xs4[i];
    acc = fmaf(w.x, xv.x, acc);
    acc = fmaf(w.y, xv.y, acc);
    acc = fmaf(w.z, xv.z, acc);
    acc = fmaf(w.w, xv.w, acc);
  }
#pragma unroll
  for (int off = 32; off > 0; off >>= 1) acc += __shfl_down(acc, off, 64);
  if (lane == 0) {
    const float hv = acc + b[row];
    h[row] = hv;
    const float key = logf(c[row]) - hv;  // c==0 -> -inf, sorts first
    unsigned int u = __float_as_uint(key);
    u = (u & 0x80000000u) ? ~u : (u | 0x80000000u);  // float -> sortable uint
    Kkey[row] = ((u64)u << 13) | (unsigned int)row;  // row < 8192 = 2^13
  }
}

// ---------------------------------------------------------------------------
// Kernel B: partial ranks. Grid (32 element-groups, 8 key-chunks) x 256 thr.
// R4 change: stage the 1024-key chunk into LDS first (8 KB, coalesced), then
// compare out of LDS. All lanes read the same kc[t] -> LDS broadcast
// (conflict-free, ~6 cyc) instead of 1024 dependent L2 loads per thread with
// 1 wave/SIMD and nothing to hide the ~200-cyc latency.
// ---------------------------------------------------------------------------
__global__ __launch_bounds__(256) void rank_k(const u64* __restrict__ Kkey,
                                              unsigned int* __restrict__ partial) {
  __shared__ u64 kc[1024];  // 8 KiB
  const int tid = threadIdx.x;
  const int i = blockIdx.x * 256 + tid;
  const u64 Ki = Kkey[i];
  const u64* __restrict__ Kc = Kkey + blockIdx.y * 1024;
#pragma unroll
  for (int j = 0; j < 4; ++j) kc[j * 256 + tid] = Kc[j * 256 + tid];
  __syncthreads();
  unsigned int cnt = 0;
#pragma unroll 16
  for (int t = 0; t < 1024; ++t) cnt += (kc[t] < Ki) ? 1u : 0u;
  partial[blockIdx.y * N + i] = cnt;
}

// ---------------------------------------------------------------------------
// Kernel C: budget-constrained softmax, one 1024-thread block, NO SORT.
// (verified bit-exact vs reference in R3; unchanged)
// ---------------------------------------------------------------------------
__global__ __launch_bounds__(1024) void bcsoftmax_k(const float* __restrict__ h,
                                                    const float* __restrict__ c,
                                                    const unsigned int* __restrict__ partial,
                                                    float* __restrict__ out) {
  __shared__ float hbuf[N];          // 32 KiB (reused as ybuf at the end)
  __shared__ float cbuf[N];          // 32 KiB
  __shared__ unsigned int sperm[N];  // 32 KiB: sorted pos -> original idx
  __shared__ float red[32];
  __shared__ float bcast[4];
  const int tid = threadIdx.x;
  const int lane = tid & 63;
  const int wid = tid >> 6;

  // ---- Phase 0a: coalesced stage of h, c into LDS; running max of h -------
  float lmax = -INFINITY;
  {
    const float4* h4 = reinterpret_cast<const float4*>(h);
    const float4* c4 = reinterpret_cast<const float4*>(c);
    const float4 a0 = h4[tid * 2], a1 = h4[tid * 2 + 1];
    const float4 b0 = c4[tid * 2], b1 = c4[tid * 2 + 1];
    reinterpret_cast<float4*>(hbuf)[tid * 2]     = a0;
    reinterpret_cast<float4*>(hbuf)[tid * 2 + 1] = a1;
    reinterpret_cast<float4*>(cbuf)[tid * 2]     = b0;
    reinterpret_cast<float4*>(cbuf)[tid * 2 + 1] = b1;
    lmax = fmaxf(lmax, fmaxf(fmaxf(a0.x, a0.y), fmaxf(a0.z, a0.w)));
    lmax = fmaxf(lmax, fmaxf(fmaxf(a1.x, a1.y), fmaxf(a1.z, a1.w)));
  }
#pragma unroll
  for (int off = 32; off > 0; off >>= 1) lmax = fmaxf(lmax, __shfl_down(lmax, off, 64));
  if (lane == 0) red[wid] = lmax;

  // ---- Phase 0b: sum rank partials, scatter permutation into LDS ----------
#pragma unroll
  for (int p = 0; p < 8; ++p) {
    const int g = p * 1024 + tid;  // coalesced ownership for partial reads
    unsigned int rank = 0;
#pragma unroll
    for (int y = 0; y < 8; ++y) rank += partial[y * N + g];
    sperm[rank] = (unsigned int)g;
  }
  __syncthreads();  // hbuf, cbuf, sperm, red all visible
  if (tid == 0) {
    float mm = red[0];
    for (int i = 1; i < 16; ++i) mm = fmaxf(mm, red[i]);
    bcast[0] = mm;
  }
  __syncthreads();
  const float M = bcast[0];

  // ---- Phase C: gather sorted xs, cs from LDS; chunk totals ---------------
  int idx[8];
  float xs[8], cs[8], e[8];
  float cloc = 0.f, eloc = 0.f;
  {
    const uint4* sp4 = reinterpret_cast<const uint4*>(sperm);
    const uint4 i0 = sp4[tid * 2], i1 = sp4[tid * 2 + 1];
    idx[0] = i0.x; idx[1] = i0.y; idx[2] = i0.z; idx[3] = i0.w;
    idx[4] = i1.x; idx[5] = i1.y; idx[6] = i1.z; idx[7] = i1.w;
  }
#pragma unroll
  for (int p = 0; p < 8; ++p) {
    xs[p] = hbuf[idx[p]];
    cs[p] = cbuf[idx[p]];
  }
#pragma unroll
  for (int p = 0; p < 8; ++p) {
    e[p] = expf(xs[p] - M);
    cloc += cs[p];
    eloc += e[p];
  }

  // ---- Phase D: block scans via shuffles ----------------------------------
  float cinc = cloc;
#pragma unroll
  for (int off = 1; off < 64; off <<= 1) {
    const float t = __shfl_up(cinc, off, 64);
    if (lane >= off) cinc += t;
  }
  float cwex = __shfl_up(cinc, 1, 64);
  if (lane == 0) cwex = 0.f;
  __syncthreads();  // red reuse (was lmax partials)
  if (lane == 63) red[wid] = cinc;  // wave totals
  __syncthreads();
  if (tid < 16) {
    float winc = red[tid];
#pragma unroll
    for (int off = 1; off < 16; off <<= 1) {
      const float t = __shfl_up(winc, off, 64);
      if (lane >= off) winc += t;
    }
    float wexc = __shfl_up(winc, 1, 64);
    if (tid == 0) wexc = 0.f;
    red[tid] = wexc;
  }
  __syncthreads();
  const float cthread_excl = red[wid] + cwex;

  float sinc = eloc;
#pragma unroll
  for (int off = 1; off < 64; off <<= 1) {
    const float t = __shfl_down(sinc, off, 64);
    if (lane + off < 64) sinc += t;
  }
  float swex = __shfl_down(sinc, 1, 64);
  if (lane == 63) swex = 0.f;
  __syncthreads();
  if (lane == 0) red[16 + wid] = sinc;  // wave suffix totals
  __syncthreads();
  if (tid < 16) {
    float winc = red[16 + tid];
#pragma unroll
    for (int off = 1; off < 16; off <<= 1) {
      const float t = __shfl_down(winc, off, 64);
      if (tid + off < 16) winc += t;
    }
    float wexc = __shfl_down(winc, 1, 64);
    if (tid == 15) wexc = 0.f;
    red[16 + tid] = wexc;
  }
  __syncthreads();
  const float ethread_exsuf = red[16 + wid] + swex;

  // ---- Phase E: membership predicate + reductions -------------------------
  float lsuf[8];
  lsuf[7] = e[7];
#pragma unroll
  for (int p = 6; p >= 0; --p) lsuf[p] = e[p] + lsuf[p + 1];
  float cexc = 0.f;
  bool kb[8];
  float lm = -INFINITY, lkbc = 0.f;
#pragma unroll
  for (int p = 0; p < 8; ++p) {
    const float s = 1.0f - (cthread_excl + cexc);
    const float suff = ethread_exsuf + lsuf[p];
    const float log_r = M + logf(suff);
    const bool in_kb =
        (cs[p] == 0.0f) ||
        ((s - cs[p] > 0.0f) && (xs[p] - log_r + logf(s) > logf(cs[p])));
    kb[p] = in_kb;
    if (in_kb) lkbc += cs[p];
    else       lm = fmaxf(lm, xs[p]);
    cexc += cs[p];
  }
#pragma unroll
  for (int off = 32; off > 0; off >>= 1) {
    lm = fmaxf(lm, __shfl_down(lm, off, 64));
    lkbc += __shfl_down(lkbc, off, 64);
  }
  __syncthreads();
  if (lane == 0) { red[wid] = lm; red[16 + wid] = lkbc; }
  __syncthreads();
  if (tid == 0) {
    float mm = red[0], sc = red[16];
    for (int i = 1; i < 16; ++i) { mm = fmaxf(mm, red[i]); sc += red[16 + i]; }
    bcast[1] = mm;
    bcast[2] = 1.0f - sc;  // s2
  }
  __syncthreads();
  const float m = bcast[1];
  const float s2 = bcast[2];

  float ey[8];
  float lr = 0.f;
#pragma unroll
  for (int p = 0; p < 8; ++p) {
    ey[p] = expf(xs[p] - m);
    if (!kb[p]) lr += ey[p];
  }
#pragma unroll
  for (int off = 32; off > 0; off >>= 1) lr += __shfl_down(lr, off, 64);
  if (lane == 0) red[wid] = lr;
  __syncthreads();
  if (tid == 0) {
    float rr = red[0];
    for (int i = 1; i < 16; ++i) rr += red[i];
    bcast[3] = rr;
  }
  __syncthreads();
  const float r = bcast[3];

  // ---- Phase F: scatter to LDS, then coalesced global store ---------------
  float* ybuf = hbuf;  // hbuf no longer needed
#pragma unroll
  for (int p = 0; p < 8; ++p) {
    ybuf[idx[p]] = kb[p] ? cs[p] : s2 * ey[p] / r;
  }
  __syncthreads();
  {
    const float4* y4 = reinterpret_cast<const float4*>(ybuf);
    float4* o4 = reinterpret_cast<float4*>(out);
    o4[tid * 2]     = y4[tid * 2];
    o4[tid * 2 + 1] = y4[tid * 2 + 1];
  }
}

// ---------------------------------------------------------------------------
extern "C" void kernel_launch(void* const* d_in, const int* in_sizes, int n_in,
                              void* d_out, int out_size, void* d_ws, size_t ws_size,
                              hipStream_t stream) {
  (void)in_sizes; (void)n_in; (void)out_size; (void)ws_size;
  const float* x = (const float*)d_in[0];
  const float* c = (const float*)d_in[1];
  const float* W = (const float*)d_in[2];
  const float* b = (const float*)d_in[3];
  float* out = (float*)d_out;

  // ws layout: h (32 KB) | Kkey (64 KB) | partial (256 KB)
  char* ws = (char*)d_ws;
  float* h = (float*)ws;
  u64* Kkey = (u64*)(ws + 32768);
  unsigned int* partial = (unsigned int*)(ws + 32768 + 65536);

  matvec_k<<<N / 8, 512, 0, stream>>>(W, x, b, c, h, Kkey);
  rank_k<<<dim3(32, 8), 256, 0, stream>>>(Kkey, partial);
  bcsoftmax_k<<<1, 1024, 0, stream>>>(h, c, partial, out);
}